// Round 16
// baseline (197.000 us; speedup 1.0000x reference)
//
#include <hip/hip_runtime.h>

#define D_IN   2304
#define D_SAE  2048
#define TL     24            // T*L
#define BATCH  32
#define K_TOP  128
#define NLAT   (TL * D_SAE)  // 49152
#define NSEG   8
#define SEGLEN (NLAT / NSEG) // 6144
#define NBIN   8192
#define CCAP   512
#define KSPLIT 2
#define KS     (D_IN / KSPLIT)  // 1152
#define BK     32
#define NCH    (KS / BK)        // 36

typedef __attribute__((ext_vector_type(8))) short short8;
typedef __attribute__((ext_vector_type(4))) float f32x4;

__device__ __forceinline__ void async_cp16(const float* g, float* l) {
    __builtin_amdgcn_global_load_lds(
        (const __attribute__((address_space(1))) unsigned int*)g,
        (__attribute__((address_space(3))) unsigned int*)l, 16, 0, 0);
}

// split 8 fp32 into bf16 hi (truncated) + bf16 lo (residual, truncated)
__device__ __forceinline__ void cvt8(const float* f, short8& hi, short8& lo) {
#pragma unroll
    for (int j = 0; j < 8; ++j) {
        unsigned u = __float_as_uint(f[j]);
        hi[j] = (short)(u >> 16);
        float l = f[j] - __uint_as_float(u & 0xFFFF0000u);
        lo[j] = (short)(__float_as_uint(l) >> 16);
    }
}
__device__ __forceinline__ void cvt44(float4 a, float4 b, short8& hi, short8& lo) {
    float f[8];
    *(float4*)&f[0] = a; *(float4*)&f[4] = b;
    cvt8(f, hi, lo);
}

// ---------------- encode: bf16x3 MFMA + counted-vmcnt depth-2 pipeline ----------------
// (r10/r14-proven, byte-identical.) grid (16, TL, KSPLIT), block 256 (4 waves).
__global__ __launch_bounds__(256, 3) void enc_kernel(const float* __restrict__ x,
                                                     const float* __restrict__ W,
                                                     float* __restrict__ part) {
    __shared__ float w_s[3][BK][128];   // 48 KB -> 3 blocks/CU

    const int tid  = threadIdx.x;
    const int lane = tid & 63;
    const int wv   = tid >> 6;
    const int m0   = lane & 15;
    const int kb   = lane >> 4;
    const int tl   = blockIdx.y;
    const int ks   = blockIdx.z;
    const int col0 = blockIdx.x * 128;

    const float* Wbase = W + ((size_t)(tl * D_IN + ks * KS)) * D_SAE + col0;
    const float* xsrc0 = x + ((size_t)(m0 * TL + tl)) * D_IN + ks * KS + kb * 8;
    const float* xsrc1 = x + ((size_t)((16 + m0) * TL + tl)) * D_IN + ks * KS + kb * 8;

    float4 xr0[4], xr1[4], xr2[4];

#define STAGE(BUF, CH)                                                          \
    do {                                                                        \
        const float* Wc = Wbase + (size_t)(CH) * BK * D_SAE;                    \
        _Pragma("unroll")                                                       \
        for (int i = 0; i < 4; ++i)                                             \
            async_cp16(Wc + (size_t)(wv * 8 + 2 * i + (lane >> 5)) * D_SAE      \
                          + (lane & 31) * 4,                                    \
                       &w_s[BUF][wv * 8 + 2 * i][0]);                           \
        xr##BUF[0] = *(const float4*)(xsrc0 + (CH) * BK);                       \
        xr##BUF[1] = *(const float4*)(xsrc0 + (CH) * BK + 4);                   \
        xr##BUF[2] = *(const float4*)(xsrc1 + (CH) * BK);                       \
        xr##BUF[3] = *(const float4*)(xsrc1 + (CH) * BK + 4);                   \
    } while (0)

    f32x4 acc[2][2];
#pragma unroll
    for (int mt = 0; mt < 2; ++mt)
#pragma unroll
        for (int nt = 0; nt < 2; ++nt) acc[mt][nt] = (f32x4)(0.f);

#define COMPUTE(BUF)                                                            \
    do {                                                                        \
        const float(*ws)[128] = w_s[BUF];                                       \
        short8 a0h, a0l, a1h, a1l;                                              \
        cvt44(xr##BUF[0], xr##BUF[1], a0h, a0l);                                \
        cvt44(xr##BUF[2], xr##BUF[3], a1h, a1l);                                \
        _Pragma("unroll")                                                       \
        for (int nt = 0; nt < 2; ++nt) {                                        \
            float wf[8];                                                        \
            _Pragma("unroll")                                                   \
            for (int j = 0; j < 8; ++j)                                         \
                wf[j] = ws[kb * 8 + j][wv * 32 + nt * 16 + m0];                 \
            short8 bhi, blo;                                                    \
            cvt8(wf, bhi, blo);                                                 \
            acc[0][nt] = __builtin_amdgcn_mfma_f32_16x16x32_bf16(a0h, bhi, acc[0][nt], 0, 0, 0); \
            acc[0][nt] = __builtin_amdgcn_mfma_f32_16x16x32_bf16(a0h, blo, acc[0][nt], 0, 0, 0); \
            acc[0][nt] = __builtin_amdgcn_mfma_f32_16x16x32_bf16(a0l, bhi, acc[0][nt], 0, 0, 0); \
            acc[1][nt] = __builtin_amdgcn_mfma_f32_16x16x32_bf16(a1h, bhi, acc[1][nt], 0, 0, 0); \
            acc[1][nt] = __builtin_amdgcn_mfma_f32_16x16x32_bf16(a1h, blo, acc[1][nt], 0, 0, 0); \
            acc[1][nt] = __builtin_amdgcn_mfma_f32_16x16x32_bf16(a1l, bhi, acc[1][nt], 0, 0, 0); \
        }                                                                       \
    } while (0)

#define ITER(BUF, NXT, C)                                                       \
    do {                                                                        \
        if ((C) + 1 < NCH) { asm volatile("s_waitcnt vmcnt(8)" ::: "memory"); } \
        else               { asm volatile("s_waitcnt vmcnt(0)" ::: "memory"); } \
        __builtin_amdgcn_s_barrier();                                           \
        if ((C) + 2 < NCH) STAGE(NXT, (C) + 2);                                 \
        COMPUTE(BUF);                                                           \
    } while (0)

    STAGE(0, 0);
    STAGE(1, 1);
    for (int c3 = 0; c3 < NCH; c3 += 3) {   // NCH = 36 = 3*12
        ITER(0, 2, c3);
        ITER(1, 0, c3 + 1);
        ITER(2, 1, c3 + 2);
    }
#undef ITER
#undef COMPUTE
#undef STAGE

    float* pp = part + ((size_t)ks * BATCH) * NLAT + (size_t)tl * D_SAE + col0;
#pragma unroll
    for (int mt = 0; mt < 2; ++mt)
#pragma unroll
        for (int nt = 0; nt < 2; ++nt)
#pragma unroll
            for (int r = 0; r < 4; ++r)
                pp[(size_t)(mt * 16 + kb * 4 + r) * NLAT + wv * 32 + nt * 16 + m0] =
                    acc[mt][nt][r];
}

// ------- reduce partials + bias -> pre; zero z (full-chip BW) + loss ----------
__global__ void reduce_kernel(const float* __restrict__ part,
                              const float* __restrict__ b_enc,
                              float* __restrict__ pre,
                              float* __restrict__ z,
                              float* __restrict__ loss) {
    int i = (blockIdx.x * blockDim.x + threadIdx.x) * 4;   // [0, BATCH*NLAT)
    const size_t S = (size_t)BATCH * NLAT;
    float4 v = *(const float4*)&b_enc[i & (D_SAE - 1)];
#pragma unroll
    for (int s = 0; s < KSPLIT; s++) {
        float4 p = *(const float4*)&part[i + s * S];
        v.x += p.x; v.y += p.y; v.z += p.z; v.w += p.w;
    }
    *(float4*)&pre[i] = v;
    z[i] = 0.f; z[i + 1] = 0.f; z[i + 2] = 0.f; z[i + 3] = 0.f;  // z only 4B-aligned
    if (i == 0) *loss = 0.f;
}

// ---- hist8: per-(segment,row) private LDS histogram; coalesced global writes ----
__global__ __launch_bounds__(256) void hist8_kernel(const float* __restrict__ pre,
                                                    unsigned* __restrict__ ghist,
                                                    int* __restrict__ selcnt,
                                                    int* __restrict__ candcnt) {
    const int seg = blockIdx.x, b = blockIdx.y, tid = threadIdx.x;
    __shared__ unsigned h[NBIN];
    for (int i = tid; i < NBIN; i += 256) h[i] = 0;
    if (seg == 0 && tid == 0) { selcnt[b] = 0; candcnt[b] = 0; }
    __syncthreads();

    const float* row = pre + (size_t)b * NLAT + seg * SEGLEN;
    for (int i = 4 * tid; i < SEGLEN; i += 1024) {
        float4 v = *(const float4*)&row[i];
#pragma unroll
        for (int j = 0; j < 4; j++) {
            unsigned u   = __float_as_uint(((const float*)&v)[j]);
            unsigned key = u ^ ((u >> 31) ? 0xFFFFFFFFu : 0x80000000u); // monotone
            atomicAdd(&h[key >> 19], 1u);
        }
    }
    __syncthreads();
    unsigned* gh = ghist + (size_t)b * NBIN * NSEG;
    for (int i = tid; i < NBIN; i += 256) gh[(size_t)i * NSEG + seg] = h[i];
}

// ---- thresh: merge 8 seg-hists, parallel suffix scan -> per-row T / hi ----
__global__ __launch_bounds__(512) void thresh_kernel(const unsigned* __restrict__ ghist,
                                                     int* __restrict__ Tb,
                                                     int* __restrict__ hib) {
    const int b = blockIdx.x, tid = threadIdx.x;
    __shared__ unsigned hist[NBIN];
    __shared__ unsigned tsum[512], scan[512];
    __shared__ int sT, shi;
    const unsigned* gh = ghist + (size_t)b * NBIN * NSEG;
    for (int i = tid; i < NBIN; i += 512) {
        uint4 a = *(const uint4*)&gh[(size_t)i * NSEG];
        uint4 c = *(const uint4*)&gh[(size_t)i * NSEG + 4];
        hist[i] = a.x + a.y + a.z + a.w + c.x + c.y + c.z + c.w;
    }
    __syncthreads();

    unsigned local = 0;
    const int base = tid * (NBIN / 512);
#pragma unroll
    for (int j = 0; j < NBIN / 512; j++) local += hist[base + j];
    tsum[tid] = local;
    scan[tid] = local;
    __syncthreads();
    for (int d = 1; d < 512; d <<= 1) {             // suffix-inclusive scan
        unsigned v = scan[tid] + ((tid + d < 512) ? scan[tid + d] : 0u);
        __syncthreads();
        scan[tid] = v;
        __syncthreads();
    }
    const unsigned suf_e = scan[tid] - tsum[tid];   // suffix-exclusive
    if (suf_e < K_TOP && suf_e + tsum[tid] >= K_TOP) {   // exactly one thread
        unsigned c = suf_e;
        for (int j = NBIN / 512 - 1; j >= 0; j--) {
            int bin = base + j;
            if (c + hist[bin] >= K_TOP) { sT = bin; shi = (int)c; break; }
            c += hist[bin];
        }
    }
    __syncthreads();
    if (tid == 0) { Tb[b] = sT; hib[b] = shi; }
}

// ---- select: strict winners + tie candidates, 8-way parallel per row ----
__global__ __launch_bounds__(256) void select_kernel(const float* __restrict__ pre,
                                                     const int* __restrict__ Tb,
                                                     int* __restrict__ selcnt,
                                                     int* __restrict__ sel_idx,
                                                     float* __restrict__ sel_val,
                                                     int* __restrict__ candcnt,
                                                     unsigned* __restrict__ cand_key,
                                                     int* __restrict__ cand_idx,
                                                     float* __restrict__ cand_val,
                                                     float* __restrict__ z) {
    const int seg = blockIdx.x, b = blockIdx.y;
    const int T = Tb[b];
    const float* row  = pre + (size_t)b * NLAT;
    float*       zrow = z   + (size_t)b * NLAT;
    for (int i = seg * SEGLEN + threadIdx.x * 4; i < (seg + 1) * SEGLEN; i += 1024) {
        float4 v = *(const float4*)&row[i];
#pragma unroll
        for (int j = 0; j < 4; ++j) {
            float f      = ((const float*)&v)[j];
            unsigned u   = __float_as_uint(f);
            unsigned key = u ^ ((u >> 31) ? 0xFFFFFFFFu : 0x80000000u);
            int bin      = (int)(key >> 19);
            if (bin > T) {
                int p = atomicAdd(&selcnt[b], 1);
                float rl = fmaxf(f, 0.f);
                sel_idx[b * K_TOP + p] = i + j;
                sel_val[b * K_TOP + p] = rl;
                zrow[i + j] = rl;
            } else if (bin == T) {
                int q = atomicAdd(&candcnt[b], 1);
                if (q < CCAP) {
                    cand_key[b * CCAP + q] = key;
                    cand_idx[b * CCAP + q] = i + j;
                    cand_val[b * CCAP + q] = f;
                }
            }
        }
    }
}

// ---- tie: rank candidates in threshold bin, fill remaining slots ----
__global__ __launch_bounds__(64) void tie_kernel(const int* __restrict__ hib,
                                                 const int* __restrict__ candcnt,
                                                 const unsigned* __restrict__ cand_key,
                                                 const int* __restrict__ cand_idx,
                                                 const float* __restrict__ cand_val,
                                                 int* __restrict__ sel_idx,
                                                 float* __restrict__ sel_val,
                                                 float* __restrict__ z) {
    const int b = blockIdx.x, tid = threadIdx.x;
    const int nc = min(candcnt[b], CCAP);
    const int hi = hib[b], need = K_TOP - hi;
    __shared__ unsigned k_s[CCAP];
    __shared__ int      i_s[CCAP];
    __shared__ float    v_s[CCAP];
    for (int c = tid; c < nc; c += 64) {
        k_s[c] = cand_key[b * CCAP + c];
        i_s[c] = cand_idx[b * CCAP + c];
        v_s[c] = cand_val[b * CCAP + c];
    }
    __syncthreads();
    for (int c = tid; c < nc; c += 64) {
        unsigned kc = k_s[c]; int ic = i_s[c];
        int rank = 0;
        for (int j = 0; j < nc; ++j)
            rank += (k_s[j] > kc) || (k_s[j] == kc && i_s[j] < ic);  // lower idx wins
        if (rank < need) {
            float rl = fmaxf(v_s[c], 0.f);
            sel_idx[b * K_TOP + hi + rank] = ic;
            sel_val[b * K_TOP + hi + rank] = rl;
            z[(size_t)b * NLAT + ic] = rl;
        }
    }
}

// ---------------- sparse decode + x_hat + loss ----------------
__global__ __launch_bounds__(256) void dec_kernel(const float* __restrict__ Wd,
                                                  const float* __restrict__ b_dec,
                                                  const float* __restrict__ x,
                                                  const int* __restrict__ sel_idx,
                                                  const float* __restrict__ sel_val,
                                                  float* __restrict__ xhat,
                                                  float* __restrict__ loss) {
    const int tl = blockIdx.x, b = blockIdx.y, tid = threadIdx.x;
    float acc[9];
#pragma unroll
    for (int r = 0; r < 9; r++) acc[r] = b_dec[tl * D_IN + tid + r * 256];

    __shared__ int   s_idx[K_TOP];
    __shared__ float s_val[K_TOP];
    if (tid < K_TOP) { s_idx[tid] = sel_idx[b * K_TOP + tid];
                       s_val[tid] = sel_val[b * K_TOP + tid]; }
    __syncthreads();

    for (int j = 0; j < K_TOP; j++) {
        int f = s_idx[j];
        if ((f >> 11) == tl) {                 // D_SAE = 2048
            float v = s_val[j];
            const float* wrow = Wd + (size_t)f * D_IN;
#pragma unroll
            for (int r = 0; r < 9; r++)
                acc[r] = fmaf(v, wrow[tid + r * 256], acc[r]);
        }
    }

    const float* xr = x    + ((size_t)b * TL + tl) * D_IN;
    float*       xo = xhat + ((size_t)b * TL + tl) * D_IN;
    float lsum = 0.f;
#pragma unroll
    for (int r = 0; r < 9; r++) {
        float d = acc[r] - xr[tid + r * 256];
        xo[tid + r * 256] = acc[r];
        lsum += d * d;
    }
    __shared__ float red[256];
    red[tid] = lsum; __syncthreads();
    for (int s = 128; s > 0; s >>= 1) {
        if (tid < s) red[tid] += red[tid + s];
        __syncthreads();
    }
    if (tid == 0) atomicAdd(loss, red[0] * (1.0f / (BATCH * TL)));
}

extern "C" void kernel_launch(void* const* d_in, const int* in_sizes, int n_in,
                              void* d_out, int out_size, void* d_ws, size_t ws_size,
                              hipStream_t stream) {
    const float* x     = (const float*)d_in[0];
    const float* W_enc = (const float*)d_in[1];
    const float* W_dec = (const float*)d_in[2];
    const float* b_enc = (const float*)d_in[3];
    const float* b_dec = (const float*)d_in[4];

    float* out  = (float*)d_out;
    float* loss = out;
    float* xhat = out + 1;
    float* z    = out + 1 + (size_t)BATCH * TL * D_IN;

    const size_t S = (size_t)BATCH * NLAT;
    float*    part     = (float*)d_ws;
    float*    pre      = part + (size_t)KSPLIT * S;
    unsigned* ghist    = (unsigned*)(pre + S);               // 32*8192*8 = 8 MB
    int*      Tb       = (int*)(ghist + (size_t)BATCH * NBIN * NSEG);
    int*      hib      = Tb + BATCH;
    int*      selcnt   = hib + BATCH;
    int*      candcnt  = selcnt + BATCH;
    int*      sel_idx  = candcnt + BATCH;                    // 32*128
    float*    sel_val  = (float*)(sel_idx + BATCH * K_TOP);
    unsigned* cand_key = (unsigned*)(sel_val + BATCH * K_TOP);  // 32*512
    int*      cand_idx = (int*)(cand_key + BATCH * CCAP);
    float*    cand_val = (float*)(cand_idx + BATCH * CCAP);

    enc_kernel<<<dim3(16, TL, KSPLIT), 256, 0, stream>>>(x, W_enc, part);
    reduce_kernel<<<(int)(S / 1024), 256, 0, stream>>>(part, b_enc, pre, z, loss);
    hist8_kernel<<<dim3(NSEG, BATCH), 256, 0, stream>>>(pre, ghist, selcnt, candcnt);
    thresh_kernel<<<BATCH, 512, 0, stream>>>(ghist, Tb, hib);
    select_kernel<<<dim3(NSEG, BATCH), 256, 0, stream>>>(pre, Tb, selcnt, sel_idx,
                                                         sel_val, candcnt, cand_key,
                                                         cand_idx, cand_val, z);
    tie_kernel<<<BATCH, 64, 0, stream>>>(hib, candcnt, cand_key, cand_idx, cand_val,
                                         sel_idx, sel_val, z);
    dec_kernel<<<dim3(TL, BATCH), 256, 0, stream>>>(W_dec, b_dec, x, sel_idx, sel_val,
                                                    xhat, loss);
}

// Round 17
// 158.160 us; speedup vs baseline: 1.2456x; 1.2456x over previous
//
#include <hip/hip_runtime.h>

#define D_IN   2304
#define D_SAE  2048
#define TL     24            // T*L
#define BATCH  32
#define K_TOP  128
#define NLAT   (TL * D_SAE)  // 49152
#define NBIN   8192
#define CAP    2048
#define KSPLIT 2
#define KS     (D_IN / KSPLIT)  // 1152
#define BK     32
#define NCH    (KS / BK)        // 36
#define TOPK_T 512

typedef __attribute__((ext_vector_type(8))) short short8;
typedef __attribute__((ext_vector_type(4))) float f32x4;

__device__ __forceinline__ void async_cp16(const float* g, float* l) {
    __builtin_amdgcn_global_load_lds(
        (const __attribute__((address_space(1))) unsigned int*)g,
        (__attribute__((address_space(3))) unsigned int*)l, 16, 0, 0);
}

// split 8 fp32 into bf16 hi (truncated) + bf16 lo (residual, truncated)
__device__ __forceinline__ void cvt8(const float* f, short8& hi, short8& lo) {
#pragma unroll
    for (int j = 0; j < 8; ++j) {
        unsigned u = __float_as_uint(f[j]);
        hi[j] = (short)(u >> 16);
        float l = f[j] - __uint_as_float(u & 0xFFFF0000u);
        lo[j] = (short)(__float_as_uint(l) >> 16);
    }
}
__device__ __forceinline__ void cvt44(float4 a, float4 b, short8& hi, short8& lo) {
    float f[8];
    *(float4*)&f[0] = a; *(float4*)&f[4] = b;
    cvt8(f, hi, lo);
}

// ---------------- encode: bf16x3 MFMA + counted-vmcnt depth-2 pipeline ----------------
// grid (16, TL, KSPLIT), block 256 (4 waves). Block tile 32 batches x 128 cols;
// wave tile 32x32. 3 W LDS buffers (compile-time rotation), ONE s_barrier/chunk,
// steady vmcnt(8). pre = xh*wh + xh*wl + xl*wh (bf16 MFMA, fp32 acc).
__global__ __launch_bounds__(256, 3) void enc_kernel(const float* __restrict__ x,
                                                     const float* __restrict__ W,
                                                     float* __restrict__ part) {
    __shared__ float w_s[3][BK][128];   // 48 KB -> 3 blocks/CU

    const int tid  = threadIdx.x;
    const int lane = tid & 63;
    const int wv   = tid >> 6;
    const int m0   = lane & 15;         // MFMA row (batch) / col within 16-tile
    const int kb   = lane >> 4;         // K-block (8 elems)
    const int tl   = blockIdx.y;
    const int ks   = blockIdx.z;
    const int col0 = blockIdx.x * 128;

    const float* Wbase = W + ((size_t)(tl * D_IN + ks * KS)) * D_SAE + col0;
    const float* xsrc0 = x + ((size_t)(m0 * TL + tl)) * D_IN + ks * KS + kb * 8;
    const float* xsrc1 = x + ((size_t)((16 + m0) * TL + tl)) * D_IN + ks * KS + kb * 8;

    float4 xr0[4], xr1[4], xr2[4];      // per-buffer A-fragment regs (literal-indexed)

    // group = 4 W DMA (each 1KB: 2 rows x 512B) + 4 x float4 reg loads = 8 vm ops
#define STAGE(BUF, CH)                                                          \
    do {                                                                        \
        const float* Wc = Wbase + (size_t)(CH) * BK * D_SAE;                    \
        _Pragma("unroll")                                                       \
        for (int i = 0; i < 4; ++i)                                             \
            async_cp16(Wc + (size_t)(wv * 8 + 2 * i + (lane >> 5)) * D_SAE      \
                          + (lane & 31) * 4,                                    \
                       &w_s[BUF][wv * 8 + 2 * i][0]);                           \
        xr##BUF[0] = *(const float4*)(xsrc0 + (CH) * BK);                       \
        xr##BUF[1] = *(const float4*)(xsrc0 + (CH) * BK + 4);                   \
        xr##BUF[2] = *(const float4*)(xsrc1 + (CH) * BK);                       \
        xr##BUF[3] = *(const float4*)(xsrc1 + (CH) * BK + 4);                   \
    } while (0)

    f32x4 acc[2][2];
#pragma unroll
    for (int mt = 0; mt < 2; ++mt)
#pragma unroll
        for (int nt = 0; nt < 2; ++nt) acc[mt][nt] = (f32x4)(0.f);

#define COMPUTE(BUF)                                                            \
    do {                                                                        \
        const float(*ws)[128] = w_s[BUF];                                       \
        short8 a0h, a0l, a1h, a1l;                                              \
        cvt44(xr##BUF[0], xr##BUF[1], a0h, a0l);                                \
        cvt44(xr##BUF[2], xr##BUF[3], a1h, a1l);                                \
        _Pragma("unroll")                                                       \
        for (int nt = 0; nt < 2; ++nt) {                                        \
            float wf[8];                                                        \
            _Pragma("unroll")                                                   \
            for (int j = 0; j < 8; ++j)                                         \
                wf[j] = ws[kb * 8 + j][wv * 32 + nt * 16 + m0];                 \
            short8 bhi, blo;                                                    \
            cvt8(wf, bhi, blo);                                                 \
            acc[0][nt] = __builtin_amdgcn_mfma_f32_16x16x32_bf16(a0h, bhi, acc[0][nt], 0, 0, 0); \
            acc[0][nt] = __builtin_amdgcn_mfma_f32_16x16x32_bf16(a0h, blo, acc[0][nt], 0, 0, 0); \
            acc[0][nt] = __builtin_amdgcn_mfma_f32_16x16x32_bf16(a0l, bhi, acc[0][nt], 0, 0, 0); \
            acc[1][nt] = __builtin_amdgcn_mfma_f32_16x16x32_bf16(a1h, bhi, acc[1][nt], 0, 0, 0); \
            acc[1][nt] = __builtin_amdgcn_mfma_f32_16x16x32_bf16(a1h, blo, acc[1][nt], 0, 0, 0); \
            acc[1][nt] = __builtin_amdgcn_mfma_f32_16x16x32_bf16(a1l, bhi, acc[1][nt], 0, 0, 0); \
        }                                                                       \
    } while (0)

    // iter: wait own group C (in-order retirement: <=8 outstanding => group C
    // landed) -> barrier (all waves' C landed) -> stage C+2 -> compute C.
#define ITER(BUF, NXT, C)                                                       \
    do {                                                                        \
        if ((C) + 1 < NCH) { asm volatile("s_waitcnt vmcnt(8)" ::: "memory"); } \
        else               { asm volatile("s_waitcnt vmcnt(0)" ::: "memory"); } \
        __builtin_amdgcn_s_barrier();                                           \
        if ((C) + 2 < NCH) STAGE(NXT, (C) + 2);                                 \
        COMPUTE(BUF);                                                           \
    } while (0)

    STAGE(0, 0);
    STAGE(1, 1);
    for (int c3 = 0; c3 < NCH; c3 += 3) {   // NCH = 36 = 3*12
        ITER(0, 2, c3);
        ITER(1, 0, c3 + 1);
        ITER(2, 1, c3 + 2);
    }
#undef ITER
#undef COMPUTE
#undef STAGE

    // C layout (m89-verified): row(batch) = mt*16 + kb*4 + r, col = nt*16 + m0
    float* pp = part + ((size_t)ks * BATCH) * NLAT + (size_t)tl * D_SAE + col0;
#pragma unroll
    for (int mt = 0; mt < 2; ++mt)
#pragma unroll
        for (int nt = 0; nt < 2; ++nt)
#pragma unroll
            for (int r = 0; r < 4; ++r)
                pp[(size_t)(mt * 16 + kb * 4 + r) * NLAT + wv * 32 + nt * 16 + m0] =
                    acc[mt][nt][r];
}

// ------- reduce partials + bias -> pre; zero z (full-chip BW) + loss ----------
__global__ void reduce_kernel(const float* __restrict__ part,
                              const float* __restrict__ b_enc,
                              float* __restrict__ pre,
                              float* __restrict__ z,
                              float* __restrict__ loss) {
    int i = (blockIdx.x * blockDim.x + threadIdx.x) * 4;   // [0, BATCH*NLAT)
    const size_t S = (size_t)BATCH * NLAT;
    float4 v = *(const float4*)&b_enc[i & (D_SAE - 1)];
#pragma unroll
    for (int s = 0; s < KSPLIT; s++) {
        float4 p = *(const float4*)&part[i + s * S];
        v.x += p.x; v.y += p.y; v.z += p.z; v.w += p.w;
    }
    *(float4*)&pre[i] = v;
    z[i] = 0.f; z[i + 1] = 0.f; z[i + 2] = 0.f; z[i + 3] = 0.f;  // z only 4B-aligned
    if (i == 0) *loss = 0.f;
}

// -------- topk: LDS hist + parallel suffix scan; winners only ----------------
__global__ __launch_bounds__(TOPK_T) void topk_kernel(const float* __restrict__ pre,
                                                      int* __restrict__ sel_idx,
                                                      float* __restrict__ sel_val,
                                                      float* __restrict__ z) {
    const int b   = blockIdx.x;
    const int tid = threadIdx.x;
    __shared__ unsigned hist[NBIN];
    __shared__ unsigned cand_key[CAP];
    __shared__ int      cand_idx[CAP];
    __shared__ unsigned tsum[TOPK_T];
    __shared__ unsigned scan[TOPK_T];
    __shared__ int s_T, s_hi, s_ccnt, s_sel;

    const float* row  = pre + (size_t)b * NLAT;
    float*       zrow = z   + (size_t)b * NLAT;
    for (int i = tid; i < NBIN; i += TOPK_T) hist[i] = 0;
    if (tid == 0) { s_ccnt = 0; s_sel = 0; }
    __syncthreads();

    for (int i = 4 * tid; i < NLAT; i += 4 * TOPK_T) {
        float4 v = *(const float4*)&row[i];
#pragma unroll
        for (int j = 0; j < 4; j++) {
            unsigned u   = __float_as_uint(((const float*)&v)[j]);
            unsigned key = u ^ ((u >> 31) ? 0xFFFFFFFFu : 0x80000000u); // monotone
            atomicAdd(&hist[key >> 19], 1u);
        }
    }
    __syncthreads();

    unsigned local = 0;
    const int base = tid * (NBIN / TOPK_T);
#pragma unroll
    for (int j = 0; j < NBIN / TOPK_T; j++) local += hist[base + j];
    tsum[tid] = local;
    scan[tid] = local;
    __syncthreads();
    for (int d = 1; d < TOPK_T; d <<= 1) {          // suffix-inclusive scan, 9 steps
        unsigned v = scan[tid] + ((tid + d < TOPK_T) ? scan[tid + d] : 0u);
        __syncthreads();
        scan[tid] = v;
        __syncthreads();
    }
    const unsigned suf_e = scan[tid] - tsum[tid];   // suffix-exclusive
    if (suf_e < K_TOP && suf_e + tsum[tid] >= K_TOP) {   // exactly one thread
        unsigned c = suf_e;
        for (int j = NBIN / TOPK_T - 1; j >= 0; j--) {
            int bin = base + j;
            if (c + hist[bin] >= K_TOP) { s_T = bin; s_hi = (int)c; break; }
            c += hist[bin];
        }
    }
    __syncthreads();

    const int T = s_T;
    for (int i = 4 * tid; i < NLAT; i += 4 * TOPK_T) {
        float4 v = *(const float4*)&row[i];
#pragma unroll
        for (int j = 0; j < 4; j++) {
            float f      = ((const float*)&v)[j];
            unsigned u   = __float_as_uint(f);
            unsigned key = u ^ ((u >> 31) ? 0xFFFFFFFFu : 0x80000000u);
            int bin      = (int)(key >> 19);
            if (bin > T) {                 // winners only; z pre-zeroed in reduce
                int p = atomicAdd(&s_sel, 1);
                float rl = fmaxf(f, 0.f);
                sel_idx[b * K_TOP + p] = i + j;
                sel_val[b * K_TOP + p] = rl;
                zrow[i + j] = rl;
            } else if (bin == T) {
                int p = atomicAdd(&s_ccnt, 1);
                if (p < CAP) { cand_key[p] = key; cand_idx[p] = i + j; }
            }
        }
    }
    __syncthreads();

    const int need = K_TOP - s_hi;
    const int nc   = min(s_ccnt, CAP);
    for (int c = tid; c < nc; c += TOPK_T) {
        unsigned kc = cand_key[c]; int ic = cand_idx[c];
        int rank = 0;
        for (int j = 0; j < nc; j++) {
            unsigned kj = cand_key[j]; int ij = cand_idx[j];
            rank += (kj > kc) || (kj == kc && ij < ic);   // ties -> lower index wins
        }
        if (rank < need) {
            int p = atomicAdd(&s_sel, 1);
            float rl = fmaxf(row[ic], 0.f);
            sel_idx[b * K_TOP + p] = ic;
            sel_val[b * K_TOP + p] = rl;
            zrow[ic] = rl;
        }
    }
}

// ---------------- sparse decode + x_hat + loss ----------------
__global__ __launch_bounds__(256) void dec_kernel(const float* __restrict__ Wd,
                                                  const float* __restrict__ b_dec,
                                                  const float* __restrict__ x,
                                                  const int* __restrict__ sel_idx,
                                                  const float* __restrict__ sel_val,
                                                  float* __restrict__ xhat,
                                                  float* __restrict__ loss) {
    const int tl = blockIdx.x, b = blockIdx.y, tid = threadIdx.x;
    float acc[9];
#pragma unroll
    for (int r = 0; r < 9; r++) acc[r] = b_dec[tl * D_IN + tid + r * 256];

    __shared__ int   s_idx[K_TOP];
    __shared__ float s_val[K_TOP];
    if (tid < K_TOP) { s_idx[tid] = sel_idx[b * K_TOP + tid];
                       s_val[tid] = sel_val[b * K_TOP + tid]; }
    __syncthreads();

    for (int j = 0; j < K_TOP; j++) {
        int f = s_idx[j];
        if ((f >> 11) == tl) {                 // D_SAE = 2048
            float v = s_val[j];
            const float* wrow = Wd + (size_t)f * D_IN;
#pragma unroll
            for (int r = 0; r < 9; r++)
                acc[r] = fmaf(v, wrow[tid + r * 256], acc[r]);
        }
    }

    const float* xr = x    + ((size_t)b * TL + tl) * D_IN;
    float*       xo = xhat + ((size_t)b * TL + tl) * D_IN;
    float lsum = 0.f;
#pragma unroll
    for (int r = 0; r < 9; r++) {
        float d = acc[r] - xr[tid + r * 256];
        xo[tid + r * 256] = acc[r];
        lsum += d * d;
    }
    __shared__ float red[256];
    red[tid] = lsum; __syncthreads();
    for (int s = 128; s > 0; s >>= 1) {
        if (tid < s) red[tid] += red[tid + s];
        __syncthreads();
    }
    if (tid == 0) atomicAdd(loss, red[0] * (1.0f / (BATCH * TL)));
}

extern "C" void kernel_launch(void* const* d_in, const int* in_sizes, int n_in,
                              void* d_out, int out_size, void* d_ws, size_t ws_size,
                              hipStream_t stream) {
    const float* x     = (const float*)d_in[0];
    const float* W_enc = (const float*)d_in[1];
    const float* W_dec = (const float*)d_in[2];
    const float* b_enc = (const float*)d_in[3];
    const float* b_dec = (const float*)d_in[4];

    float* out  = (float*)d_out;
    float* loss = out;
    float* xhat = out + 1;
    float* z    = out + 1 + (size_t)BATCH * TL * D_IN;

    const size_t S = (size_t)BATCH * NLAT;
    float* part    = (float*)d_ws;
    float* pre     = part + (size_t)KSPLIT * S;
    int*   sel_idx = (int*)(pre + S);
    float* sel_val = (float*)(sel_idx + BATCH * K_TOP);

    enc_kernel<<<dim3(16, TL, KSPLIT), 256, 0, stream>>>(x, W_enc, part);
    reduce_kernel<<<(int)(S / 1024), 256, 0, stream>>>(part, b_enc, pre, z, loss);
    topk_kernel<<<BATCH, TOPK_T, 0, stream>>>(pre, sel_idx, sel_val, z);
    dec_kernel<<<dim3(TL, BATCH), 256, 0, stream>>>(W_dec, b_dec, x, sel_idx, sel_val,
                                                    xhat, loss);
}